// Round 15
// baseline (258.820 us; speedup 1.0000x reference)
//
#include <hip/hip_runtime.h>
#include <hip/hip_bf16.h>

typedef __hip_bfloat16 bf16;
typedef unsigned int uint;
typedef unsigned short ushort;

#define N_NODES 100000
#define N_EDGES_C 1600000
#define NSB2 1568          // buckets: dst>>6 (64 dsts each); 1568*64=100352
#define NSB2P 1792         // padded counter array size
#define NCLS 8             // scatter classes (blockIdx&7 ~ XCD); per-class sub-regions
#define SUBCAP 320         // per-bucket-per-class capacity (mean 128, +17 sigma)
#define CNT_TOT (NSB2P * NCLS)   // 14336 counters
#define RND 2048           // edges per radix block (782 blocks)
#define EPB (RND / 256)    // 8 edges per thread
#define NBIN 64            // degree bins (Poisson(16): max deg ~50)
#define G_RAD ((N_EDGES_C + RND - 1) / RND)   // 782 radix blocks in fused kernel
#define HCAP 1536          // per-64-dst LDS esrc capacity (mean 1020, +16 sigma)
#define NCHUNK 8           // src chunks (src>>14): kv locality windows ~1-2MB
#define KEYN (64 * NCHUNK) // 512

// ---------- runtime dtype helpers ----------
__device__ __forceinline__ float ldf(const void* p, long i, int isbf) {
    return isbf ? __bfloat162float(((const bf16*)p)[i]) : ((const float*)p)[i];
}
__device__ __forceinline__ int ldidx(const int* ei, long pos, int is64) {
    return is64 ? ei[2 * pos] : ei[pos];   // int64 LE: low word at 2*pos
}
__device__ __forceinline__ ushort bfb(float x) {   // f32 -> bf16 bits (RNE)
    bf16 h = __float2bfloat16(x);
    return *(ushort*)&h;
}
__device__ __forceinline__ float bl(uint u) { return __uint_as_float(u << 16); }        // low bf16
__device__ __forceinline__ float bh(uint u) { return __uint_as_float(u & 0xFFFF0000u); } // high bf16

// in-block dtype detectors (wave 0 computes, LDS-broadcast by caller)
__device__ __forceinline__ int detect_isbf_w0(const void* emb) {
    int t = threadIdx.x;          // caller guarantees t < 64
    const bf16* pb = (const bf16*)emb;
    int bad = 0;
    for (int i = t; i < 256; i += 64) {
        float v = __bfloat162float(pb[i]);
        if (!(v > -1.0e6f && v < 1.0e6f)) bad++;   // f32-viewed-as-bf16 => ~42% huge/nan
    }
#pragma unroll
    for (int m = 32; m >= 1; m >>= 1) bad += __shfl_xor(bad, m, 64);
    return (bad <= 8) ? 1 : 0;
}
__device__ __forceinline__ int detect_is64_w0(const int* ei) {
    int t = threadIdx.x;          // caller guarantees t < 64
    int nz = 0;
    for (int i = 2 * t + 1; i < 256; i += 128) nz += (ei[i] != 0) ? 1 : 0;
#pragma unroll
    for (int m = 32; m >= 1; m >>= 1) nz += __shfl_xor(nz, m, 64);
    return (nz == 0) ? 1 : 0;
}

// ---------- CSR-build-in-LDS (shared by both gathers; iterates 8 class sub-regions) ----------
struct BuildS { int dcnt[KEYN]; int dexcl[KEYN]; int hbin[NBIN]; int hbase[NBIN]; int hcur[NBIN]; };

__device__ __forceinline__ void build_csr(
    int sbh, const int* __restrict__ curSB, const uint* __restrict__ pairsSB,
    BuildS* b, int* sEsrc, int* sRB, int* sRE, int* sPerm) {
    int t = threadIdx.x;
    for (int i = t; i < KEYN; i += 256) b->dcnt[i] = 0;
    if (t < NBIN) { b->hbin[t] = 0; b->hcur[t] = 0; }
    if (t < 64) sPerm[t] = -1;
    __syncthreads();
    for (int cls = 0; cls < NCLS; cls++) {
        int nc = min(curSB[sbh * NCLS + cls], SUBCAP);
        const uint* sp = pairsSB + ((size_t)sbh * NCLS + cls) * SUBCAP;
        for (int i = t; i < nc; i += 256) {
            uint pk = sp[i];
            int key = (int)((pk >> 17) & 63) * NCHUNK + (int)((pk & 0x1FFFFu) >> 14);
            atomicAdd(&b->dcnt[key], 1);
        }
    }
    __syncthreads();
    int mybin = -1;
    if (t < 64) {
        const int kb = t * NCHUNK;
        int sum = 0;
#pragma unroll
        for (int j = 0; j < NCHUNK; j++) sum += b->dcnt[kb + j];
        int v = sum;                           // degree of dst-local t
        int x = v;
#pragma unroll
        for (int off = 1; off < 64; off <<= 1) {
            int u2 = __shfl_up(x, off, 64);
            if (t >= off) x += u2;
        }
        int myExcl = x - v;
        int run = myExcl;
#pragma unroll
        for (int j = 0; j < NCHUNK; j++) { b->dexcl[kb + j] = run; run += b->dcnt[kb + j]; }
        sRB[t] = min(myExcl, HCAP);
        sRE[t] = min(myExcl + v, HCAP);
        int dst = sbh * 64 + t;
        if (dst < N_NODES) {
            mybin = min(v, NBIN - 1);
            atomicAdd(&b->hbin[mybin], 1);
        }
    }
    __syncthreads();
    if (t < 64) {
        int hv = b->hbin[t];
        int sfx = hv;
#pragma unroll
        for (int off = 1; off < 64; off <<= 1) {
            int u2 = __shfl_down(sfx, off, 64);
            if (t + off < 64) sfx += u2;
        }
        b->hbase[t] = sfx - hv;
    }
    __syncthreads();
    if (t < 64 && mybin >= 0) {
        int r = atomicAdd(&b->hcur[mybin], 1);
        sPerm[b->hbase[mybin] + r] = t;
    }
    for (int cls = 0; cls < NCLS; cls++) {
        int nc = min(curSB[sbh * NCLS + cls], SUBCAP);
        const uint* sp = pairsSB + ((size_t)sbh * NCLS + cls) * SUBCAP;
        for (int i = t; i < nc; i += 256) {
            uint pk = sp[i];
            int key = (int)((pk >> 17) & 63) * NCHUNK + (int)((pk & 0x1FFFFu) >> 14);
            int p2 = atomicAdd(&b->dexcl[key], 1);
            if (p2 < HCAP) sEsrc[p2] = (int)(pk & 0x1FFFF);
        }
    }
    __syncthreads();
}

// ---------- node linear body (layer-1; self-casting from raw weight ptrs) ----------
__device__ __forceinline__ void node_linear_body32(
    const void* __restrict__ X,
    const void* Wq, const void* bq, const void* Wk, const void* bk,
    const void* Wv, const void* bv, const void* Ws, const void* bs,
    float* __restrict__ q, ushort* __restrict__ kvb, float* __restrict__ s,
    int bid, float* __restrict__ sW, float* __restrict__ sbias, float* __restrict__ sX,
    int* sFlag) {
    const int NPB = 32;           // nodes per block (TPN=8)
    int t = threadIdx.x;
    if (t < 64) { int f = detect_isbf_w0(X); if (t == 0) *sFlag = f; }
    __syncthreads();
    int isbf = *sFlag;

    for (int i = t; i < 1024; i += 256) {
        sW[i]        = ldf(Wq, i, isbf);
        sW[1024 + i] = ldf(Wk, i, isbf);
        sW[2048 + i] = ldf(Wv, i, isbf);
        sW[3072 + i] = ldf(Ws, i, isbf);
    }
    if (t < 32) {
        sbias[t]      = ldf(bq, t, isbf);
        sbias[32 + t] = ldf(bk, t, isbf);
        sbias[64 + t] = ldf(bv, t, isbf);
        sbias[96 + t] = ldf(bs, t, isbf);
    }
    const int base = bid * NPB * 32;
    if (isbf) {
        for (int i = t; i < NPB * 32; i += 256) {
            int g = base + i;
            float xv = (g < N_NODES * 32) ? __bfloat162float(((const bf16*)X)[g]) : 0.0f;
            sX[(i >> 5) * 36 + (i & 31)] = xv;
        }
    } else {
        for (int i = t; i < NPB * 32; i += 256) {
            int g = base + i;
            sX[(i >> 5) * 36 + (i & 31)] = (g < N_NODES * 32) ? ((const float*)X)[g] : 0.0f;
        }
    }
    __syncthreads();

    int l = t / 8;
    int c4 = (t % 8) * 4;
    int n = bid * NPB + l;
    if (n >= N_NODES) return;

    float xr[32];
#pragma unroll
    for (int j = 0; j < 8; j++) {
        float4 t4 = *(const float4*)&sX[l * 36 + 4 * j];
        xr[4 * j] = t4.x; xr[4 * j + 1] = t4.y; xr[4 * j + 2] = t4.z; xr[4 * j + 3] = t4.w;
    }
    float acc[4][4];
#pragma unroll
    for (int m = 0; m < 4; m++)
#pragma unroll
        for (int j = 0; j < 4; j++) acc[m][j] = sbias[m * 32 + c4 + j];

#pragma unroll
    for (int tt = 0; tt < 32; tt++) {
#pragma unroll
        for (int m = 0; m < 4; m++) {
            float4 w = *(const float4*)&sW[(m * 32 + tt) * 32 + c4];
            acc[m][0] += xr[tt] * w.x;
            acc[m][1] += xr[tt] * w.y;
            acc[m][2] += xr[tt] * w.z;
            acc[m][3] += xr[tt] * w.w;
        }
    }
    size_t o = (size_t)n * 32 + c4;
    *(float4*)&q[o] = make_float4(acc[0][0], acc[0][1], acc[0][2], acc[0][3]);
    *(float4*)&s[o] = make_float4(acc[3][0], acc[3][1], acc[3][2], acc[3][3]);
    size_t okv = (size_t)n * 64 + c4;
    ushort4 kp = make_ushort4(bfb(acc[1][0]), bfb(acc[1][1]), bfb(acc[1][2]), bfb(acc[1][3]));
    ushort4 vp = make_ushort4(bfb(acc[2][0]), bfb(acc[2][1]), bfb(acc[2][2]), bfb(acc[2][3]));
    *(ushort4*)&kvb[okv]      = kp;
    *(ushort4*)&kvb[okv + 32] = vp;
}

// ---------- fused: setup(block 0) || radix_a (per-class scatter) || node_linear<32> ----------
struct RadixS { int cnt[NSB2P]; int gbase[NSB2P]; };
struct LinS { float sW[4096]; float sbias[128]; float sX[32 * 36]; };
union alignas(16) FusedS { RadixS r; LinS l; };

__global__ void __launch_bounds__(256, 4) fused_all(
    const int* __restrict__ ei, const void* __restrict__ emb,
    const void* Wq1, const void* bq1, const void* Wk1, const void* bk1,
    const void* Wv1, const void* bv1, const void* Ws1, const void* bs1,
    const void* Wq2, const void* bq2, const void* Wk2, const void* bk2,
    const void* Wv2, const void* bv2, const void* Ws2, const void* bs2,
    const void* Wo, const void* bo,
    int* __restrict__ flags, float* __restrict__ wp2, float* __restrict__ bp2,
    float* __restrict__ woF,
    int* __restrict__ curSB, uint* __restrict__ pairsSB,
    float* __restrict__ q, ushort* __restrict__ kvb, float* __restrict__ s) {
    __shared__ FusedS u;
    __shared__ int sFlag;
    int t = threadIdx.x;

    if (blockIdx.x == 0) {
        // ---- residual setup: flags + gather-stage params (wp2/bp2/woF) ----
        if (t < 64) {
            int f0 = detect_isbf_w0(emb);
            int f1 = detect_is64_w0(ei);
            if (t == 0) { flags[0] = f0; flags[1] = f1; sFlag = f0; }
        }
        __syncthreads();
        int isbf = sFlag;
        for (int i = t; i < 512; i += 256) {
            wp2[i]        = ldf(Wq2, i, isbf);
            wp2[512 + i]  = ldf(Wk2, i, isbf);
            wp2[1024 + i] = ldf(Wv2, i, isbf);
            wp2[1536 + i] = ldf(Ws2, i, isbf);
        }
        if (t < 32) woF[t] = ldf(Wo, t, isbf);
        if (t < 16) {
            bp2[t] = ldf(bq2, t, isbf); bp2[16 + t] = ldf(bk2, t, isbf);
            bp2[32 + t] = ldf(bv2, t, isbf); bp2[48 + t] = ldf(bs2, t, isbf);
        }
        if (t < 2) woF[32 + t] = ldf(bo, t, isbf);
        return;
    }
    if (blockIdx.x > G_RAD) {
        node_linear_body32(emb, Wq1, bq1, Wk1, bk1, Wv1, bv1, Ws1, bs1,
                           q, kvb, s, (int)blockIdx.x - 1 - G_RAD,
                           u.l.sW, u.l.sbias, u.l.sX, &sFlag);
        return;
    }
    // ---- radix body: count + per-class direct scatter into dst>>6 buckets.
    // Class = blockIdx&7 (~XCD proxy): consecutive slots of a (bucket,class)
    // sub-region are written by same-class blocks -> lines fill within one L2
    // instead of ping-ponging across XCDs (R14: 12x write amplification).
    int* cnt = u.r.cnt; int* gbase = u.r.gbase;
    int rblk = (int)blockIdx.x - 1;
    const int cls = (int)(blockIdx.x & 7);
    for (int i = t; i < NSB2P; i += 256) cnt[i] = 0;
    if (t < 64) { int f = detect_is64_w0(ei); if (t == 0) sFlag = f; }
    __syncthreads();
    const int is64 = sFlag;
    long base = (long)rblk * RND;

    int mySb[EPB]; int myRank[EPB]; uint myPk[EPB];
#pragma unroll
    for (int r = 0; r < EPB; r++) {
        long e = base + r * 256 + t;
        mySb[r] = -1;
        if (e < N_EDGES_C) {
            int d = ldidx(ei, (long)N_EDGES_C + e, is64);
            int src = ldidx(ei, e, is64);
            int sb = d >> 6;                       // 0..1562
            myPk[r] = (uint)src | ((uint)(d & 63) << 17);
            myRank[r] = atomicAdd(&cnt[sb], 1);
            mySb[r] = sb;
        }
    }
    __syncthreads();
    for (int i = t; i < NSB2P; i += 256)
        gbase[i] = (cnt[i] > 0) ? atomicAdd(&curSB[i * NCLS + cls], cnt[i]) : 0;
    __syncthreads();
#pragma unroll
    for (int r = 0; r < EPB; r++) {
        if (mySb[r] >= 0) {
            int gp = gbase[mySb[r]] + myRank[r];
            if (gp < SUBCAP)
                pairsSB[((size_t)mySb[r] * NCLS + cls) * SUBCAP + gp] = myPk[r];
        }
    }
}

// ---------- gather L1: CSR-build-in-LDS + 4-deep k/v-split gather + fused L2 linear ----------
__global__ void gather_attn_l1(const int* __restrict__ curSB, const uint* __restrict__ pairsSB,
                               const float* __restrict__ q, const ushort* __restrict__ kvb,
                               const float* __restrict__ s,
                               const float* __restrict__ wp2,   // [4][32][16] f32
                               const float* __restrict__ bp2,   // [4][16] f32
                               float* __restrict__ q2o, ushort* __restrict__ kvb2o,
                               float* __restrict__ s2o) {
    const int D = 32;
    const int LPD = 4;       // lanes per dst
    const int G = 16;        // dst groups per wave
    __shared__ float sW2[2048];
    __shared__ float sb2[64];
    union GU { BuildS b; float sH[64 * 36]; };   // build arrays dead before sH is written
    __shared__ GU gu;
    __shared__ int sEsrc[HCAP];                  // 6 KB
    __shared__ int sDst[64], sPerm[64], sRB[64], sRE[64];

    int sbh = blockIdx.x;
    for (int i = threadIdx.x; i < 2048; i += 256) sW2[i] = wp2[i];
    if (threadIdx.x < 64) sb2[threadIdx.x] = bp2[threadIdx.x];
    build_csr(sbh, curSB, pairsSB, &gu.b, sEsrc, sRB, sRE, sPerm);

    int lane = threadIdx.x & 63;
    int wave = threadIdx.x >> 6;       // block-local wave 0..3
    int g = lane / LPD;
    int c = lane % LPD;                // dims 8c..8c+7
    int rank = wave * G + g;           // 0..63, degree-descending
    int dl = sPerm[rank];              // dst-local; -1 = pad
    bool alive = (dl >= 0);            // predicate (no early return -> barrier-safe)
    int dst = sbh * 64 + dl;

    const float rsq = 0.17677669529663689f;  // 1/sqrt(32)
    float4 qa = make_float4(0.f, 0.f, 0.f, 0.f), qb = qa;
    int beg = 0, end = 0;
    if (alive) {
        qa = *(const float4*)(q + (size_t)dst * D + 8 * c);
        qb = *(const float4*)(q + (size_t)dst * D + 8 * c + 4);
        beg = sRB[dl]; end = sRE[dl];
    }

    const char* kvbase = (const char*)kvb;
    const int ROW = 4 * D;            // 128 B: [k bf16 x 32 | v bf16 x 32]
    const int koff = 16 * c;
    const int voff = 2 * D + 16 * c;

    float sum0 = 0.f, sum1 = 0.f;
    float a0[8] = {0,0,0,0,0,0,0,0};
    float a1[8] = {0,0,0,0,0,0,0,0};

    uint4 kq[4], vq[4];
#pragma unroll
    for (int r = 0; r < 4; r++) {
        int sn = (beg + r < end) ? sEsrc[beg + r] : 0;
        const char* p = kvbase + (size_t)sn * ROW;
        kq[r] = *(const uint4*)(p + koff);
        vq[r] = *(const uint4*)(p + voff);
    }

    for (int e = beg; e < end; e += 4) {
        uint4 kc[4], vc[4];
#pragma unroll
        for (int r = 0; r < 4; r++) { kc[r] = kq[r]; vc[r] = vq[r]; }
#pragma unroll
        for (int r = 0; r < 4; r++) {
            if (e + 4 + r < end) {
                const char* p = kvbase + (size_t)sEsrc[e + 4 + r] * ROW;
                kq[r] = *(const uint4*)(p + koff);
                vq[r] = *(const uint4*)(p + voff);
            }
        }
#pragma unroll
        for (int r = 0; r < 4; r++) {
            if (e + r < end) {
                uint4 kA = kc[r], vA = vc[r];
                float pd = qa.x * bl(kA.x) + qa.y * bh(kA.x) + qa.z * bl(kA.y) + qa.w * bh(kA.y)
                         + qb.x * bl(kA.z) + qb.y * bh(kA.z) + qb.z * bl(kA.w) + qb.w * bh(kA.w);
#pragma unroll
                for (int m = LPD / 2; m >= 1; m >>= 1) pd += __shfl_xor(pd, m, LPD);
                float ex = __expf(fminf(fmaxf(pd * rsq, -80.0f), 80.0f));
                if (r & 1) {
                    sum1 += ex;
                    a1[0] += bl(vA.x) * ex; a1[1] += bh(vA.x) * ex;
                    a1[2] += bl(vA.y) * ex; a1[3] += bh(vA.y) * ex;
                    a1[4] += bl(vA.z) * ex; a1[5] += bh(vA.z) * ex;
                    a1[6] += bl(vA.w) * ex; a1[7] += bh(vA.w) * ex;
                } else {
                    sum0 += ex;
                    a0[0] += bl(vA.x) * ex; a0[1] += bh(vA.x) * ex;
                    a0[2] += bl(vA.y) * ex; a0[3] += bh(vA.y) * ex;
                    a0[4] += bl(vA.z) * ex; a0[5] += bh(vA.z) * ex;
                    a0[6] += bl(vA.w) * ex; a0[7] += bh(vA.w) * ex;
                }
            }
        }
    }
    float inv = 1.0f / (sum0 + sum1 + 1e-16f);
    float4 sa = make_float4(0.f, 0.f, 0.f, 0.f), sbv = sa;
    if (alive) {
        sa  = *(const float4*)(s + (size_t)dst * D + 8 * c);
        sbv = *(const float4*)(s + (size_t)dst * D + 8 * c + 4);
    }
    float h[8];
    h[0] = (a0[0] + a1[0]) * inv + sa.x;  h[1] = (a0[1] + a1[1]) * inv + sa.y;
    h[2] = (a0[2] + a1[2]) * inv + sa.z;  h[3] = (a0[3] + a1[3]) * inv + sa.w;
    h[4] = (a0[4] + a1[4]) * inv + sbv.x; h[5] = (a0[5] + a1[5]) * inv + sbv.y;
    h[6] = (a0[6] + a1[6]) * inv + sbv.z; h[7] = (a0[7] + a1[7]) * inv + sbv.w;
#pragma unroll
    for (int j = 0; j < 8; j++) h[j] = h[j] > 0.0f ? h[j] : 0.0f;

    // fused layer-2 node linear via LDS transpose (identical accumulation order
    // to the standalone node_linear<16>); 64 nodes per block.
    int gl = wave * G + g;                    // 0..63: block-local node slot
    if (alive) {
        *(float4*)&gu.sH[gl * 36 + 8 * c]     = make_float4(h[0], h[1], h[2], h[3]);
        *(float4*)&gu.sH[gl * 36 + 8 * c + 4] = make_float4(h[4], h[5], h[6], h[7]);
    }
    if (c == 0) sDst[gl] = alive ? dst : -1;
    __syncthreads();
    int l = threadIdx.x >> 2;                 // node slot 0..63
    int c4 = (threadIdx.x & 3) * 4;           // output dims c4..c4+3
    int nd = sDst[l];
    if (nd >= 0) {
        float acc2[4][4];
#pragma unroll
        for (int m = 0; m < 4; m++)
#pragma unroll
            for (int j = 0; j < 4; j++) acc2[m][j] = sb2[m * 16 + c4 + j];
#pragma unroll
        for (int t2 = 0; t2 < 32; t2++) {
            float xv = gu.sH[l * 36 + t2];
#pragma unroll
            for (int m = 0; m < 4; m++) {
                float4 w = *(const float4*)&sW2[(m * 32 + t2) * 16 + c4];
                acc2[m][0] += xv * w.x;
                acc2[m][1] += xv * w.y;
                acc2[m][2] += xv * w.z;
                acc2[m][3] += xv * w.w;
            }
        }
        size_t o = (size_t)nd * 16 + c4;
        *(float4*)&q2o[o] = make_float4(acc2[0][0], acc2[0][1], acc2[0][2], acc2[0][3]);
        *(float4*)&s2o[o] = make_float4(acc2[3][0], acc2[3][1], acc2[3][2], acc2[3][3]);
        size_t okv = (size_t)nd * 32 + c4;
        ushort4 kp = make_ushort4(bfb(acc2[1][0]), bfb(acc2[1][1]), bfb(acc2[1][2]), bfb(acc2[1][3]));
        ushort4 vp = make_ushort4(bfb(acc2[2][0]), bfb(acc2[2][1]), bfb(acc2[2][2]), bfb(acc2[2][3]));
        *(ushort4*)&kvb2o[okv]      = kp;
        *(ushort4*)&kvb2o[okv + 16] = vp;
    }
}

// ---------- gather L2: CSR-build-in-LDS + whole-row gather (1 x 64B req/edge) ----------
__global__ void gather_attn_l2(const int* __restrict__ curSB, const uint* __restrict__ pairsSB,
                               const float* __restrict__ q, const ushort* __restrict__ kvb,
                               const float* __restrict__ s,
                               const float* __restrict__ woF,   // [32]=Wo, [32..33]=bo
                               const int* __restrict__ flags,
                               void* __restrict__ out) {
    const int D = 16;
    const int LG = 4;             // lanes per dst group = row bytes / 16
    const int KL = 2;             // k-lanes per group
    const int G  = 16;            // dsts per wave
    __shared__ BuildS bs;
    __shared__ int sEsrc[HCAP];
    __shared__ int sPerm[64], sRB[64], sRE[64];

    int sbh = blockIdx.x;
    build_csr(sbh, curSB, pairsSB, &bs, sEsrc, sRB, sRE, sPerm);
    // no barriers below -> early returns are safe

    int lane = threadIdx.x & 63;
    int wave = threadIdx.x >> 6;
    int g = lane / LG;
    int sub = lane % LG;          // 16B chunk of the row this lane owns
    bool isK = (sub < KL);
    int cv = sub - KL;            // v-lane dim chunk (dims 8cv..8cv+7)
    int rank = wave * G + g;
    int dl = sPerm[rank];
    if (dl < 0) return;
    int dst = sbh * 64 + dl;

    const float rsq = 0.25f;      // 1/sqrt(16)
    float qacc[8] = {0,0,0,0,0,0,0,0};
    if (isK) {
        float4 qa = *(const float4*)(q + (size_t)dst * D + 8 * sub);
        float4 qb = *(const float4*)(q + (size_t)dst * D + 8 * sub + 4);
        qacc[0] = qa.x; qacc[1] = qa.y; qacc[2] = qa.z; qacc[3] = qa.w;
        qacc[4] = qb.x; qacc[5] = qb.y; qacc[6] = qb.z; qacc[7] = qb.w;
    }
    int beg = sRB[dl], end = sRE[dl];

    const char* kvbase = (const char*)kvb + 16 * sub;   // this lane's chunk offset
    const int ROW = 4 * D;        // 64 B: [k bf16 x 16 | v bf16 x 16], row-aligned

    float sum = 0.f;

    uint4 rv[4];
    int sn1[4];
#pragma unroll
    for (int r = 0; r < 4; r++) {
        int sn = (beg + r < end) ? sEsrc[beg + r] : 0;
        rv[r] = *(const uint4*)(kvbase + (size_t)sn * ROW);
    }
#pragma unroll
    for (int r = 0; r < 4; r++)
        sn1[r] = (beg + 4 + r < end) ? sEsrc[beg + 4 + r] : 0;

    for (int e = beg; e < end; e += 4) {
        uint4 rc[4];
#pragma unroll
        for (int r = 0; r < 4; r++) rc[r] = rv[r];
#pragma unroll
        for (int r = 0; r < 4; r++) {
            if (e + 4 + r < end)
                rv[r] = *(const uint4*)(kvbase + (size_t)sn1[r] * ROW);
        }
#pragma unroll
        for (int r = 0; r < 4; r++) {
            if (e + 8 + r < end) sn1[r] = sEsrc[e + 8 + r];
        }
#pragma unroll
        for (int r = 0; r < 4; r++) {
            if (e + r < end) {
                uint4 rA = rc[r];
                float pd = 0.f;
                if (isK) {
                    pd = qacc[0] * bl(rA.x) + qacc[1] * bh(rA.x)
                       + qacc[2] * bl(rA.y) + qacc[3] * bh(rA.y)
                       + qacc[4] * bl(rA.z) + qacc[5] * bh(rA.z)
                       + qacc[6] * bl(rA.w) + qacc[7] * bh(rA.w);
                }
                pd += __shfl_xor(pd, 1, KL);            // reduce across 2 k-lanes
                float pdx = __shfl_xor(pd, KL, LG);     // k->v broadcast
                float pdf = isK ? pd : pdx;
                float ex = __expf(fminf(fmaxf(pdf * rsq, -80.0f), 80.0f));
                sum += ex;
                if (!isK) {
                    qacc[0] += bl(rA.x) * ex; qacc[1] += bh(rA.x) * ex;
                    qacc[2] += bl(rA.y) * ex; qacc[3] += bh(rA.y) * ex;
                    qacc[4] += bl(rA.z) * ex; qacc[5] += bh(rA.z) * ex;
                    qacc[6] += bl(rA.w) * ex; qacc[7] += bh(rA.w) * ex;
                }
            }
        }
    }
    float inv = 1.0f / (sum + 1e-16f);   // sum identical on all LG lanes of the group
    float p0 = 0.f, p1 = 0.f;
    if (!isK) {
        float4 sa  = *(const float4*)(s + (size_t)dst * D + 8 * cv);
        float4 sbv = *(const float4*)(s + (size_t)dst * D + 8 * cv + 4);
        float h[8];
        h[0] = qacc[0] * inv + sa.x;  h[1] = qacc[1] * inv + sa.y;
        h[2] = qacc[2] * inv + sa.z;  h[3] = qacc[3] * inv + sa.w;
        h[4] = qacc[4] * inv + sbv.x; h[5] = qacc[5] * inv + sbv.y;
        h[6] = qacc[6] * inv + sbv.z; h[7] = qacc[7] * inv + sbv.w;
#pragma unroll
        for (int j = 0; j < 8; j++) h[j] = h[j] > 0.0f ? h[j] : 0.0f;
#pragma unroll
        for (int j = 0; j < 8; j++) {
            p0 += h[j] * woF[(8 * cv + j) * 2 + 0];
            p1 += h[j] * woF[(8 * cv + j) * 2 + 1];
        }
    }
    p0 += __shfl_xor(p0, 1, 2);
    p1 += __shfl_xor(p1, 1, 2);
    if (sub == KL) {
        float o0 = p0 + woF[32];
        float o1 = p1 + woF[33];
        if (flags[0]) {
            ((bf16*)out)[dst * 2 + 0] = __float2bfloat16(o0);
            ((bf16*)out)[dst * 2 + 1] = __float2bfloat16(o1);
        } else {
            ((float*)out)[dst * 2 + 0] = o0;
            ((float*)out)[dst * 2 + 1] = o1;
        }
    }
}

extern "C" void kernel_launch(void* const* d_in, const int* in_sizes, int n_in,
                              void* d_out, int out_size, void* d_ws, size_t ws_size,
                              hipStream_t stream) {
    const int* ei  = (const int*)d_in[0];
    const void* emb = d_in[1];
    const void *Wq1 = d_in[2],  *bq1 = d_in[3];
    const void *Wk1 = d_in[4],  *bk1 = d_in[5];
    const void *Wv1 = d_in[6],  *bv1 = d_in[7];
    const void *Ws1 = d_in[8],  *bs1 = d_in[9];
    const void *Wq2 = d_in[10], *bq2 = d_in[11];
    const void *Wk2 = d_in[12], *bk2 = d_in[13];
    const void *Wv2 = d_in[14], *bv2 = d_in[15];
    const void *Ws2 = d_in[16], *bs2 = d_in[17];
    const void *Wo  = d_in[18], *bo  = d_in[19];

    const size_t ND   = (size_t)N_NODES * 32;   // 3.2M floats
    const size_t ND16 = (size_t)N_NODES * 16;   // 1.6M floats
    const size_t SBTOT = (size_t)NSB2 * NCLS * SUBCAP;   // 4,014,080 (pairsSB, 16 MB)
    float* base   = (float*)d_ws;
    int*   flags  = (int*)base;                  // 64
    float* wp2    = base + 64;                   // 2048
    float* bp2    = wp2 + 2048;                  // 64
    float* woF    = bp2 + 64;                    // 64
    int*   curSB  = (int*)(woF + 64);            // CNT_TOT (14336)
    float* p      = (float*)(curSB + CNT_TOT);
    p = (float*)(((uintptr_t)p + 127) & ~(uintptr_t)127);   // 128B-align kv rows
    float* q      = p; p += ND;                  // layer-1 q (f32)
    float* s      = p; p += ND;                  // layer-1 skip (f32)
    ushort* kvb   = (ushort*)p; p += ND;         // layer-1 k|v packed bf16 (128B rows)
    float* q2     = p; p += ND16;                // layer-2 q
    float* s2     = p; p += ND16;                // layer-2 skip
    ushort* kvb2  = (ushort*)p; p += ND16;       // layer-2 k|v packed bf16 (64B rows)
    uint*  pairsSB = (uint*)p;                   // 16 MB
    // total ~ 77 MB

    const int B = 256;
    const int gNL32  = (N_NODES + 31) / 32;      // 3125
    const int gFused = 1 + G_RAD + gNL32;        // setup block + radix + NL

    // 0: zero bucket counters (stream-ordered, graph-capturable)
    hipMemsetAsync(curSB, 0, CNT_TOT * sizeof(int), stream);

    // 1: setup(block 0) || radix pass (per-class scatter) || layer-1 node linears
    fused_all<<<gFused, B, 0, stream>>>(ei, emb,
        Wq1, bq1, Wk1, bk1, Wv1, bv1, Ws1, bs1,
        Wq2, bq2, Wk2, bk2, Wv2, bv2, Ws2, bs2, Wo, bo,
        flags, wp2, bp2, woF, curSB, pairsSB, q, kvb, s);

    // 2: layer-1 attention (CSR built in-block from pairsSB) + relu + fused L2 linear
    gather_attn_l1<<<NSB2, B, 0, stream>>>(
        curSB, pairsSB, q, kvb, s, wp2, bp2, q2, kvb2, s2);

    // 3: layer-2 attention (CSR built in-block) + relu + output linear
    gather_attn_l2<<<NSB2, B, 0, stream>>>(
        curSB, pairsSB, q2, kvb2, s2, woF, flags, d_out);
}

// Round 16
// 235.329 us; speedup vs baseline: 1.0998x; 1.0998x over previous
//
#include <hip/hip_runtime.h>
#include <hip/hip_bf16.h>

typedef __hip_bfloat16 bf16;
typedef unsigned int uint;
typedef unsigned short ushort;

#define N_NODES 100000
#define N_EDGES_C 1600000
#define NSB2 1568          // buckets: dst>>6 (64 dsts each); 1568*64=100352
#define NSB2P 1792         // padded counter array size
#define RND 2048           // edges per radix_a block (782 blocks)
#define EPB (RND / 256)    // 8 edges per thread
#define NBIN 64            // degree bins (Poisson(16): max deg ~50)
#define G_RAD ((N_EDGES_C + RND - 1) / RND)   // 782 radix blocks in fused kernel
#define HCAP 1536          // per-bucket capacity (mean 1020, +16 sigma)
#define NCHUNK 8           // src chunks (src>>14): kv locality windows ~1-2MB
#define KEYN (64 * NCHUNK) // 512

// ---------- runtime dtype helpers ----------
__device__ __forceinline__ float ldf(const void* p, long i, int isbf) {
    return isbf ? __bfloat162float(((const bf16*)p)[i]) : ((const float*)p)[i];
}
__device__ __forceinline__ int ldidx(const int* ei, long pos, int is64) {
    return is64 ? ei[2 * pos] : ei[pos];   // int64 LE: low word at 2*pos
}
__device__ __forceinline__ ushort bfb(float x) {   // f32 -> bf16 bits (RNE)
    bf16 h = __float2bfloat16(x);
    return *(ushort*)&h;
}
__device__ __forceinline__ float bl(uint u) { return __uint_as_float(u << 16); }        // low bf16
__device__ __forceinline__ float bh(uint u) { return __uint_as_float(u & 0xFFFF0000u); } // high bf16

// in-block dtype detectors (wave 0 computes, LDS-broadcast by caller)
__device__ __forceinline__ int detect_isbf_w0(const void* emb) {
    int t = threadIdx.x;          // caller guarantees t < 64
    const bf16* pb = (const bf16*)emb;
    int bad = 0;
    for (int i = t; i < 256; i += 64) {
        float v = __bfloat162float(pb[i]);
        if (!(v > -1.0e6f && v < 1.0e6f)) bad++;   // f32-viewed-as-bf16 => ~42% huge/nan
    }
#pragma unroll
    for (int m = 32; m >= 1; m >>= 1) bad += __shfl_xor(bad, m, 64);
    return (bad <= 8) ? 1 : 0;
}
__device__ __forceinline__ int detect_is64_w0(const int* ei) {
    int t = threadIdx.x;          // caller guarantees t < 64
    int nz = 0;
    for (int i = 2 * t + 1; i < 256; i += 128) nz += (ei[i] != 0) ? 1 : 0;
#pragma unroll
    for (int m = 32; m >= 1; m >>= 1) nz += __shfl_xor(nz, m, 64);
    return (nz == 0) ? 1 : 0;
}

// ---------- CSR-build-in-LDS (shared by both gathers; R12/R14 version) ----------
struct BuildS { int dcnt[KEYN]; int dexcl[KEYN]; int hbin[NBIN]; int hbase[NBIN]; int hcur[NBIN]; };

__device__ __forceinline__ void build_csr(
    int sbh, int n, const uint* __restrict__ srcp,
    BuildS* b, int* sEsrc, int* sRB, int* sRE, int* sPerm) {
    int t = threadIdx.x;
    for (int i = t; i < KEYN; i += 256) b->dcnt[i] = 0;
    if (t < NBIN) { b->hbin[t] = 0; b->hcur[t] = 0; }
    if (t < 64) sPerm[t] = -1;
    __syncthreads();
    for (int i = t; i < n; i += 256) {
        uint pk = srcp[i];
        int key = (int)((pk >> 17) & 63) * NCHUNK + (int)((pk & 0x1FFFFu) >> 14);
        atomicAdd(&b->dcnt[key], 1);
    }
    __syncthreads();
    int mybin = -1;
    if (t < 64) {
        const int kb = t * NCHUNK;
        int sum = 0;
#pragma unroll
        for (int j = 0; j < NCHUNK; j++) sum += b->dcnt[kb + j];
        int v = sum;                           // degree of dst-local t
        int x = v;
#pragma unroll
        for (int off = 1; off < 64; off <<= 1) {
            int u2 = __shfl_up(x, off, 64);
            if (t >= off) x += u2;
        }
        int myExcl = x - v;
        int run = myExcl;
#pragma unroll
        for (int j = 0; j < NCHUNK; j++) { b->dexcl[kb + j] = run; run += b->dcnt[kb + j]; }
        sRB[t] = myExcl;
        sRE[t] = myExcl + v;                   // total == n <= HCAP
        int dst = sbh * 64 + t;
        if (dst < N_NODES) {
            mybin = min(v, NBIN - 1);
            atomicAdd(&b->hbin[mybin], 1);
        }
    }
    __syncthreads();
    if (t < 64) {
        int hv = b->hbin[t];
        int sfx = hv;
#pragma unroll
        for (int off = 1; off < 64; off <<= 1) {
            int u2 = __shfl_down(sfx, off, 64);
            if (t + off < 64) sfx += u2;
        }
        b->hbase[t] = sfx - hv;
    }
    __syncthreads();
    if (t < 64 && mybin >= 0) {
        int r = atomicAdd(&b->hcur[mybin], 1);
        sPerm[b->hbase[mybin] + r] = t;
    }
    for (int i = t; i < n; i += 256) {
        uint pk = srcp[i];
        int key = (int)((pk >> 17) & 63) * NCHUNK + (int)((pk & 0x1FFFFu) >> 14);
        int p2 = atomicAdd(&b->dexcl[key], 1);
        sEsrc[p2] = (int)(pk & 0x1FFFF);
    }
    __syncthreads();
}

// ---------- node linear body (layer-1; self-casting from raw weight ptrs) ----------
__device__ __forceinline__ void node_linear_body32(
    const void* __restrict__ X,
    const void* Wq, const void* bq, const void* Wk, const void* bk,
    const void* Wv, const void* bv, const void* Ws, const void* bs,
    float* __restrict__ q, ushort* __restrict__ kvb, float* __restrict__ s,
    int bid, float* __restrict__ sW, float* __restrict__ sbias, float* __restrict__ sX,
    int* sFlag) {
    const int NPB = 32;           // nodes per block (TPN=8)
    int t = threadIdx.x;
    if (t < 64) { int f = detect_isbf_w0(X); if (t == 0) *sFlag = f; }
    __syncthreads();
    int isbf = *sFlag;

    for (int i = t; i < 1024; i += 256) {
        sW[i]        = ldf(Wq, i, isbf);
        sW[1024 + i] = ldf(Wk, i, isbf);
        sW[2048 + i] = ldf(Wv, i, isbf);
        sW[3072 + i] = ldf(Ws, i, isbf);
    }
    if (t < 32) {
        sbias[t]      = ldf(bq, t, isbf);
        sbias[32 + t] = ldf(bk, t, isbf);
        sbias[64 + t] = ldf(bv, t, isbf);
        sbias[96 + t] = ldf(bs, t, isbf);
    }
    const int base = bid * NPB * 32;
    if (isbf) {
        for (int i = t; i < NPB * 32; i += 256) {
            int g = base + i;
            float xv = (g < N_NODES * 32) ? __bfloat162float(((const bf16*)X)[g]) : 0.0f;
            sX[(i >> 5) * 36 + (i & 31)] = xv;
        }
    } else {
        for (int i = t; i < NPB * 32; i += 256) {
            int g = base + i;
            sX[(i >> 5) * 36 + (i & 31)] = (g < N_NODES * 32) ? ((const float*)X)[g] : 0.0f;
        }
    }
    __syncthreads();

    int l = t / 8;
    int c4 = (t % 8) * 4;
    int n = bid * NPB + l;
    if (n >= N_NODES) return;

    float xr[32];
#pragma unroll
    for (int j = 0; j < 8; j++) {
        float4 t4 = *(const float4*)&sX[l * 36 + 4 * j];
        xr[4 * j] = t4.x; xr[4 * j + 1] = t4.y; xr[4 * j + 2] = t4.z; xr[4 * j + 3] = t4.w;
    }
    float acc[4][4];
#pragma unroll
    for (int m = 0; m < 4; m++)
#pragma unroll
        for (int j = 0; j < 4; j++) acc[m][j] = sbias[m * 32 + c4 + j];

#pragma unroll
    for (int tt = 0; tt < 32; tt++) {
#pragma unroll
        for (int m = 0; m < 4; m++) {
            float4 w = *(const float4*)&sW[(m * 32 + tt) * 32 + c4];
            acc[m][0] += xr[tt] * w.x;
            acc[m][1] += xr[tt] * w.y;
            acc[m][2] += xr[tt] * w.z;
            acc[m][3] += xr[tt] * w.w;
        }
    }
    size_t o = (size_t)n * 32 + c4;
    *(float4*)&q[o] = make_float4(acc[0][0], acc[0][1], acc[0][2], acc[0][3]);
    *(float4*)&s[o] = make_float4(acc[3][0], acc[3][1], acc[3][2], acc[3][3]);
    size_t okv = (size_t)n * 64 + c4;
    ushort4 kp = make_ushort4(bfb(acc[1][0]), bfb(acc[1][1]), bfb(acc[1][2]), bfb(acc[1][3]));
    ushort4 vp = make_ushort4(bfb(acc[2][0]), bfb(acc[2][1]), bfb(acc[2][2]), bfb(acc[2][3]));
    *(ushort4*)&kvb[okv]      = kp;
    *(ushort4*)&kvb[okv + 32] = vp;
}

// ---------- fused: setup(block 0) || radix_a (direct scatter) || node_linear<32> ----------
struct RadixS { int cnt[NSB2P]; int gbase[NSB2P]; };
struct LinS { float sW[4096]; float sbias[128]; float sX[32 * 36]; };
union alignas(16) FusedS { RadixS r; LinS l; };

__global__ void __launch_bounds__(256, 4) fused_all(
    const int* __restrict__ ei, const void* __restrict__ emb,
    const void* Wq1, const void* bq1, const void* Wk1, const void* bk1,
    const void* Wv1, const void* bv1, const void* Ws1, const void* bs1,
    const void* Wq2, const void* bq2, const void* Wk2, const void* bk2,
    const void* Wv2, const void* bv2, const void* Ws2, const void* bs2,
    const void* Wo, const void* bo,
    int* __restrict__ flags, float* __restrict__ wp2, float* __restrict__ bp2,
    float* __restrict__ woF,
    int* __restrict__ curSB, uint* __restrict__ pairsSB,
    float* __restrict__ q, ushort* __restrict__ kvb, float* __restrict__ s) {
    __shared__ FusedS u;
    __shared__ int sFlag;
    int t = threadIdx.x;

    if (blockIdx.x == 0) {
        // ---- residual setup: flags + gather-stage params (wp2/bp2/woF) ----
        if (t < 64) {
            int f0 = detect_isbf_w0(emb);
            int f1 = detect_is64_w0(ei);
            if (t == 0) { flags[0] = f0; flags[1] = f1; sFlag = f0; }
        }
        __syncthreads();
        int isbf = sFlag;
        for (int i = t; i < 512; i += 256) {
            wp2[i]        = ldf(Wq2, i, isbf);
            wp2[512 + i]  = ldf(Wk2, i, isbf);
            wp2[1024 + i] = ldf(Wv2, i, isbf);
            wp2[1536 + i] = ldf(Ws2, i, isbf);
        }
        if (t < 32) woF[t] = ldf(Wo, t, isbf);
        if (t < 16) {
            bp2[t] = ldf(bq2, t, isbf); bp2[16 + t] = ldf(bk2, t, isbf);
            bp2[32 + t] = ldf(bv2, t, isbf); bp2[48 + t] = ldf(bs2, t, isbf);
        }
        if (t < 2) woF[32 + t] = ldf(bo, t, isbf);
        return;
    }
    if (blockIdx.x > G_RAD) {
        node_linear_body32(emb, Wq1, bq1, Wk1, bk1, Wv1, bv1, Ws1, bs1,
                           q, kvb, s, (int)blockIdx.x - 1 - G_RAD,
                           u.l.sW, u.l.sbias, u.l.sX, &sFlag);
        return;
    }
    // ---- radix_a body: count + direct scatter into 1568 dst-buckets (dst>>6) ----
    int* cnt = u.r.cnt; int* gbase = u.r.gbase;
    int rblk = (int)blockIdx.x - 1;
    for (int i = t; i < NSB2P; i += 256) cnt[i] = 0;
    if (t < 64) { int f = detect_is64_w0(ei); if (t == 0) sFlag = f; }
    __syncthreads();
    const int is64 = sFlag;
    long base = (long)rblk * RND;

    int mySb[EPB]; int myRank[EPB]; uint myPk[EPB];
#pragma unroll
    for (int r = 0; r < EPB; r++) {
        long e = base + r * 256 + t;
        mySb[r] = -1;
        if (e < N_EDGES_C) {
            int d = ldidx(ei, (long)N_EDGES_C + e, is64);
            int src = ldidx(ei, e, is64);
            int sb = d >> 6;                       // 0..1562
            myPk[r] = (uint)src | ((uint)(d & 63) << 17);
            myRank[r] = atomicAdd(&cnt[sb], 1);
            mySb[r] = sb;
        }
    }
    __syncthreads();
    for (int i = t; i < NSB2P; i += 256)
        gbase[i] = (cnt[i] > 0) ? atomicAdd(&curSB[i], cnt[i]) : 0;
    __syncthreads();
#pragma unroll
    for (int r = 0; r < EPB; r++) {
        if (mySb[r] >= 0) {
            int gp = gbase[mySb[r]] + myRank[r];
            if (gp < HCAP)
                pairsSB[(size_t)mySb[r] * HCAP + gp] = myPk[r];
        }
    }
}

// ---------- gather L1: CSR-build-in-LDS + 4-deep k/v-split gather + fused L2 linear ----------
__global__ void gather_attn_l1(const int* __restrict__ curSB, const uint* __restrict__ pairsSB,
                               const float* __restrict__ q, const ushort* __restrict__ kvb,
                               const float* __restrict__ s,
                               const float* __restrict__ wp2,   // [4][32][16] f32
                               const float* __restrict__ bp2,   // [4][16] f32
                               float* __restrict__ q2o, ushort* __restrict__ kvb2o,
                               float* __restrict__ s2o) {
    const int D = 32;
    const int LPD = 4;       // lanes per dst
    const int G = 16;        // dst groups per wave
    __shared__ float sW2[2048];
    __shared__ float sb2[64];
    union GU { BuildS b; float sH[64 * 36]; };   // build arrays dead before sH is written
    __shared__ GU gu;
    __shared__ int sEsrc[HCAP];                  // 6 KB
    __shared__ int sDst[64], sPerm[64], sRB[64], sRE[64];

    int sbh = blockIdx.x;
    int n = min(curSB[sbh], HCAP);
    for (int i = threadIdx.x; i < 2048; i += 256) sW2[i] = wp2[i];
    if (threadIdx.x < 64) sb2[threadIdx.x] = bp2[threadIdx.x];
    build_csr(sbh, n, pairsSB + (size_t)sbh * HCAP, &gu.b, sEsrc, sRB, sRE, sPerm);

    int lane = threadIdx.x & 63;
    int wave = threadIdx.x >> 6;       // block-local wave 0..3
    int g = lane / LPD;
    int c = lane % LPD;                // dims 8c..8c+7
    int rank = wave * G + g;           // 0..63, degree-descending
    int dl = sPerm[rank];              // dst-local; -1 = pad
    bool alive = (dl >= 0);            // predicate (no early return -> barrier-safe)
    int dst = sbh * 64 + dl;

    const float rsq = 0.17677669529663689f;  // 1/sqrt(32)
    float4 qa = make_float4(0.f, 0.f, 0.f, 0.f), qb = qa;
    int beg = 0, end = 0;
    if (alive) {
        qa = *(const float4*)(q + (size_t)dst * D + 8 * c);
        qb = *(const float4*)(q + (size_t)dst * D + 8 * c + 4);
        beg = sRB[dl]; end = sRE[dl];
    }

    const char* kvbase = (const char*)kvb;
    const int ROW = 4 * D;            // 128 B: [k bf16 x 32 | v bf16 x 32]
    const int koff = 16 * c;
    const int voff = 2 * D + 16 * c;

    float sum0 = 0.f, sum1 = 0.f;
    float a0[8] = {0,0,0,0,0,0,0,0};
    float a1[8] = {0,0,0,0,0,0,0,0};

    uint4 kq[4], vq[4];
#pragma unroll
    for (int r = 0; r < 4; r++) {
        int sn = (beg + r < end) ? sEsrc[beg + r] : 0;
        const char* p = kvbase + (size_t)sn * ROW;
        kq[r] = *(const uint4*)(p + koff);
        vq[r] = *(const uint4*)(p + voff);
    }

    for (int e = beg; e < end; e += 4) {
        uint4 kc[4], vc[4];
#pragma unroll
        for (int r = 0; r < 4; r++) { kc[r] = kq[r]; vc[r] = vq[r]; }
#pragma unroll
        for (int r = 0; r < 4; r++) {
            if (e + 4 + r < end) {
                const char* p = kvbase + (size_t)sEsrc[e + 4 + r] * ROW;
                kq[r] = *(const uint4*)(p + koff);
                vq[r] = *(const uint4*)(p + voff);
            }
        }
#pragma unroll
        for (int r = 0; r < 4; r++) {
            if (e + r < end) {
                uint4 kA = kc[r], vA = vc[r];
                float pd = qa.x * bl(kA.x) + qa.y * bh(kA.x) + qa.z * bl(kA.y) + qa.w * bh(kA.y)
                         + qb.x * bl(kA.z) + qb.y * bh(kA.z) + qb.z * bl(kA.w) + qb.w * bh(kA.w);
#pragma unroll
                for (int m = LPD / 2; m >= 1; m >>= 1) pd += __shfl_xor(pd, m, LPD);
                float ex = __expf(fminf(fmaxf(pd * rsq, -80.0f), 80.0f));
                if (r & 1) {
                    sum1 += ex;
                    a1[0] += bl(vA.x) * ex; a1[1] += bh(vA.x) * ex;
                    a1[2] += bl(vA.y) * ex; a1[3] += bh(vA.y) * ex;
                    a1[4] += bl(vA.z) * ex; a1[5] += bh(vA.z) * ex;
                    a1[6] += bl(vA.w) * ex; a1[7] += bh(vA.w) * ex;
                } else {
                    sum0 += ex;
                    a0[0] += bl(vA.x) * ex; a0[1] += bh(vA.x) * ex;
                    a0[2] += bl(vA.y) * ex; a0[3] += bh(vA.y) * ex;
                    a0[4] += bl(vA.z) * ex; a0[5] += bh(vA.z) * ex;
                    a0[6] += bl(vA.w) * ex; a0[7] += bh(vA.w) * ex;
                }
            }
        }
    }
    float inv = 1.0f / (sum0 + sum1 + 1e-16f);
    float4 sa = make_float4(0.f, 0.f, 0.f, 0.f), sbv = sa;
    if (alive) {
        sa  = *(const float4*)(s + (size_t)dst * D + 8 * c);
        sbv = *(const float4*)(s + (size_t)dst * D + 8 * c + 4);
    }
    float h[8];
    h[0] = (a0[0] + a1[0]) * inv + sa.x;  h[1] = (a0[1] + a1[1]) * inv + sa.y;
    h[2] = (a0[2] + a1[2]) * inv + sa.z;  h[3] = (a0[3] + a1[3]) * inv + sa.w;
    h[4] = (a0[4] + a1[4]) * inv + sbv.x; h[5] = (a0[5] + a1[5]) * inv + sbv.y;
    h[6] = (a0[6] + a1[6]) * inv + sbv.z; h[7] = (a0[7] + a1[7]) * inv + sbv.w;
#pragma unroll
    for (int j = 0; j < 8; j++) h[j] = h[j] > 0.0f ? h[j] : 0.0f;

    // fused layer-2 node linear via LDS transpose (identical accumulation order
    // to the standalone node_linear<16>); 64 nodes per block.
    int gl = wave * G + g;                    // 0..63: block-local node slot
    if (alive) {
        *(float4*)&gu.sH[gl * 36 + 8 * c]     = make_float4(h[0], h[1], h[2], h[3]);
        *(float4*)&gu.sH[gl * 36 + 8 * c + 4] = make_float4(h[4], h[5], h[6], h[7]);
    }
    if (c == 0) sDst[gl] = alive ? dst : -1;
    __syncthreads();
    int l = threadIdx.x >> 2;                 // node slot 0..63
    int c4 = (threadIdx.x & 3) * 4;           // output dims c4..c4+3
    int nd = sDst[l];
    if (nd >= 0) {
        float acc2[4][4];
#pragma unroll
        for (int m = 0; m < 4; m++)
#pragma unroll
            for (int j = 0; j < 4; j++) acc2[m][j] = sb2[m * 16 + c4 + j];
#pragma unroll
        for (int t2 = 0; t2 < 32; t2++) {
            float xv = gu.sH[l * 36 + t2];
#pragma unroll
            for (int m = 0; m < 4; m++) {
                float4 w = *(const float4*)&sW2[(m * 32 + t2) * 16 + c4];
                acc2[m][0] += xv * w.x;
                acc2[m][1] += xv * w.y;
                acc2[m][2] += xv * w.z;
                acc2[m][3] += xv * w.w;
            }
        }
        size_t o = (size_t)nd * 16 + c4;
        *(float4*)&q2o[o] = make_float4(acc2[0][0], acc2[0][1], acc2[0][2], acc2[0][3]);
        *(float4*)&s2o[o] = make_float4(acc2[3][0], acc2[3][1], acc2[3][2], acc2[3][3]);
        size_t okv = (size_t)nd * 32 + c4;
        ushort4 kp = make_ushort4(bfb(acc2[1][0]), bfb(acc2[1][1]), bfb(acc2[1][2]), bfb(acc2[1][3]));
        ushort4 vp = make_ushort4(bfb(acc2[2][0]), bfb(acc2[2][1]), bfb(acc2[2][2]), bfb(acc2[2][3]));
        *(ushort4*)&kvb2o[okv]      = kp;
        *(ushort4*)&kvb2o[okv + 16] = vp;
    }
}

// ---------- gather L2: CSR-build-in-LDS + whole-row gather (1 x 64B req/edge) ----------
__global__ void gather_attn_l2(const int* __restrict__ curSB, const uint* __restrict__ pairsSB,
                               const float* __restrict__ q, const ushort* __restrict__ kvb,
                               const float* __restrict__ s,
                               const float* __restrict__ woF,   // [32]=Wo, [32..33]=bo
                               const int* __restrict__ flags,
                               void* __restrict__ out) {
    const int D = 16;
    const int LG = 4;             // lanes per dst group = row bytes / 16
    const int KL = 2;             // k-lanes per group
    const int G  = 16;            // dsts per wave
    __shared__ BuildS bs;
    __shared__ int sEsrc[HCAP];
    __shared__ int sPerm[64], sRB[64], sRE[64];

    int sbh = blockIdx.x;
    int n = min(curSB[sbh], HCAP);
    build_csr(sbh, n, pairsSB + (size_t)sbh * HCAP, &bs, sEsrc, sRB, sRE, sPerm);
    // no barriers below -> early returns are safe

    int lane = threadIdx.x & 63;
    int wave = threadIdx.x >> 6;
    int g = lane / LG;
    int sub = lane % LG;          // 16B chunk of the row this lane owns
    bool isK = (sub < KL);
    int cv = sub - KL;            // v-lane dim chunk (dims 8cv..8cv+7)
    int rank = wave * G + g;
    int dl = sPerm[rank];
    if (dl < 0) return;
    int dst = sbh * 64 + dl;

    const float rsq = 0.25f;      // 1/sqrt(16)
    float qacc[8] = {0,0,0,0,0,0,0,0};
    if (isK) {
        float4 qa = *(const float4*)(q + (size_t)dst * D + 8 * sub);
        float4 qb = *(const float4*)(q + (size_t)dst * D + 8 * sub + 4);
        qacc[0] = qa.x; qacc[1] = qa.y; qacc[2] = qa.z; qacc[3] = qa.w;
        qacc[4] = qb.x; qacc[5] = qb.y; qacc[6] = qb.z; qacc[7] = qb.w;
    }
    int beg = sRB[dl], end = sRE[dl];

    const char* kvbase = (const char*)kvb + 16 * sub;   // this lane's chunk offset
    const int ROW = 4 * D;        // 64 B: [k bf16 x 16 | v bf16 x 16], row-aligned

    float sum = 0.f;

    uint4 rv[4];
    int sn1[4];
#pragma unroll
    for (int r = 0; r < 4; r++) {
        int sn = (beg + r < end) ? sEsrc[beg + r] : 0;
        rv[r] = *(const uint4*)(kvbase + (size_t)sn * ROW);
    }
#pragma unroll
    for (int r = 0; r < 4; r++)
        sn1[r] = (beg + 4 + r < end) ? sEsrc[beg + 4 + r] : 0;

    for (int e = beg; e < end; e += 4) {
        uint4 rc[4];
#pragma unroll
        for (int r = 0; r < 4; r++) rc[r] = rv[r];
#pragma unroll
        for (int r = 0; r < 4; r++) {
            if (e + 4 + r < end)
                rv[r] = *(const uint4*)(kvbase + (size_t)sn1[r] * ROW);
        }
#pragma unroll
        for (int r = 0; r < 4; r++) {
            if (e + 8 + r < end) sn1[r] = sEsrc[e + 8 + r];
        }
#pragma unroll
        for (int r = 0; r < 4; r++) {
            if (e + r < end) {
                uint4 rA = rc[r];
                float pd = 0.f;
                if (isK) {
                    pd = qacc[0] * bl(rA.x) + qacc[1] * bh(rA.x)
                       + qacc[2] * bl(rA.y) + qacc[3] * bh(rA.y)
                       + qacc[4] * bl(rA.z) + qacc[5] * bh(rA.z)
                       + qacc[6] * bl(rA.w) + qacc[7] * bh(rA.w);
                }
                pd += __shfl_xor(pd, 1, KL);            // reduce across 2 k-lanes
                float pdx = __shfl_xor(pd, KL, LG);     // k->v broadcast
                float pdf = isK ? pd : pdx;
                float ex = __expf(fminf(fmaxf(pdf * rsq, -80.0f), 80.0f));
                sum += ex;
                if (!isK) {
                    qacc[0] += bl(rA.x) * ex; qacc[1] += bh(rA.x) * ex;
                    qacc[2] += bl(rA.y) * ex; qacc[3] += bh(rA.y) * ex;
                    qacc[4] += bl(rA.z) * ex; qacc[5] += bh(rA.z) * ex;
                    qacc[6] += bl(rA.w) * ex; qacc[7] += bh(rA.w) * ex;
                }
            }
        }
    }
    float inv = 1.0f / (sum + 1e-16f);   // sum identical on all LG lanes of the group
    float p0 = 0.f, p1 = 0.f;
    if (!isK) {
        float4 sa  = *(const float4*)(s + (size_t)dst * D + 8 * cv);
        float4 sbv = *(const float4*)(s + (size_t)dst * D + 8 * cv + 4);
        float h[8];
        h[0] = qacc[0] * inv + sa.x;  h[1] = qacc[1] * inv + sa.y;
        h[2] = qacc[2] * inv + sa.z;  h[3] = qacc[3] * inv + sa.w;
        h[4] = qacc[4] * inv + sbv.x; h[5] = qacc[5] * inv + sbv.y;
        h[6] = qacc[6] * inv + sbv.z; h[7] = qacc[7] * inv + sbv.w;
#pragma unroll
        for (int j = 0; j < 8; j++) h[j] = h[j] > 0.0f ? h[j] : 0.0f;
#pragma unroll
        for (int j = 0; j < 8; j++) {
            p0 += h[j] * woF[(8 * cv + j) * 2 + 0];
            p1 += h[j] * woF[(8 * cv + j) * 2 + 1];
        }
    }
    p0 += __shfl_xor(p0, 1, 2);
    p1 += __shfl_xor(p1, 1, 2);
    if (sub == KL) {
        float o0 = p0 + woF[32];
        float o1 = p1 + woF[33];
        if (flags[0]) {
            ((bf16*)out)[dst * 2 + 0] = __float2bfloat16(o0);
            ((bf16*)out)[dst * 2 + 1] = __float2bfloat16(o1);
        } else {
            ((float*)out)[dst * 2 + 0] = o0;
            ((float*)out)[dst * 2 + 1] = o1;
        }
    }
}

extern "C" void kernel_launch(void* const* d_in, const int* in_sizes, int n_in,
                              void* d_out, int out_size, void* d_ws, size_t ws_size,
                              hipStream_t stream) {
    const int* ei  = (const int*)d_in[0];
    const void* emb = d_in[1];
    const void *Wq1 = d_in[2],  *bq1 = d_in[3];
    const void *Wk1 = d_in[4],  *bk1 = d_in[5];
    const void *Wv1 = d_in[6],  *bv1 = d_in[7];
    const void *Ws1 = d_in[8],  *bs1 = d_in[9];
    const void *Wq2 = d_in[10], *bq2 = d_in[11];
    const void *Wk2 = d_in[12], *bk2 = d_in[13];
    const void *Wv2 = d_in[14], *bv2 = d_in[15];
    const void *Ws2 = d_in[16], *bs2 = d_in[17];
    const void *Wo  = d_in[18], *bo  = d_in[19];

    const size_t ND   = (size_t)N_NODES * 32;   // 3.2M floats
    const size_t ND16 = (size_t)N_NODES * 16;   // 1.6M floats
    const size_t SBTOT = (size_t)NSB2 * HCAP;   // 2,408,448 (pairsSB)
    float* base   = (float*)d_ws;
    int*   flags  = (int*)base;                  // 64
    float* wp2    = base + 64;                   // 2048
    float* bp2    = wp2 + 2048;                  // 64
    float* woF    = bp2 + 64;                    // 64
    int*   curSB  = (int*)(woF + 64);            // NSB2P (1792)
    float* p      = (float*)(curSB + NSB2P);
    p = (float*)(((uintptr_t)p + 127) & ~(uintptr_t)127);   // 128B-align kv rows
    float* q      = p; p += ND;                  // layer-1 q (f32)
    float* s      = p; p += ND;                  // layer-1 skip (f32)
    ushort* kvb   = (ushort*)p; p += ND;         // layer-1 k|v packed bf16 (128B rows)
    float* q2     = p; p += ND16;                // layer-2 q
    float* s2     = p; p += ND16;                // layer-2 skip
    ushort* kvb2  = (ushort*)p; p += ND16;       // layer-2 k|v packed bf16 (64B rows)
    uint*  pairsSB = (uint*)p;                   // 9.6 MB
    // total ~ 70 MB

    const int B = 256;
    const int gNL32  = (N_NODES + 31) / 32;      // 3125
    const int gFused = 1 + G_RAD + gNL32;        // setup block + radix + NL

    // 0: zero bucket counters (stream-ordered, graph-capturable)
    hipMemsetAsync(curSB, 0, NSB2P * sizeof(int), stream);

    // 1: setup(block 0) || radix pass A (direct scatter) || layer-1 node linears
    fused_all<<<gFused, B, 0, stream>>>(ei, emb,
        Wq1, bq1, Wk1, bk1, Wv1, bv1, Ws1, bs1,
        Wq2, bq2, Wk2, bk2, Wv2, bv2, Ws2, bs2, Wo, bo,
        flags, wp2, bp2, woF, curSB, pairsSB, q, kvb, s);

    // 2: layer-1 attention (CSR built in-block from pairsSB) + relu + fused L2 linear
    gather_attn_l1<<<NSB2, B, 0, stream>>>(
        curSB, pairsSB, q, kvb, s, wp2, bp2, q2, kvb2, s2);

    // 3: layer-2 attention (CSR built in-block) + relu + output linear
    gather_attn_l2<<<NSB2, B, 0, stream>>>(
        curSB, pairsSB, q2, kvb2, s2, woF, flags, d_out);
}

// Round 17
// 234.254 us; speedup vs baseline: 1.1049x; 1.0046x over previous
//
#include <hip/hip_runtime.h>
#include <hip/hip_bf16.h>

typedef __hip_bfloat16 bf16;
typedef unsigned int uint;
typedef unsigned short ushort;

#define N_NODES 100000
#define N_EDGES_C 1600000
#define NSB2 1568          // buckets: dst>>6 (64 dsts each); 1568*64=100352
#define NSB2P 1792         // padded counter array size
#define RND 2048           // edges per radix_a block (782 blocks)
#define EPB (RND / 256)    // 8 edges per thread
#define NBIN 64            // degree bins (Poisson(16): max deg ~50)
#define G_RAD ((N_EDGES_C + RND - 1) / RND)   // 782 radix blocks in fused kernel
#define HCAP 1536          // per-bucket capacity (mean 1020, +16 sigma)
#define NCHUNK 8           // src chunks (src>>14): kv locality windows ~1-2MB
#define KEYN (64 * NCHUNK) // 512

// ---------- runtime dtype helpers ----------
__device__ __forceinline__ float ldf(const void* p, long i, int isbf) {
    return isbf ? __bfloat162float(((const bf16*)p)[i]) : ((const float*)p)[i];
}
__device__ __forceinline__ int ldidx(const int* ei, long pos, int is64) {
    return is64 ? ei[2 * pos] : ei[pos];   // int64 LE: low word at 2*pos
}
__device__ __forceinline__ ushort bfb(float x) {   // f32 -> bf16 bits (RNE)
    bf16 h = __float2bfloat16(x);
    return *(ushort*)&h;
}
__device__ __forceinline__ float bl(uint u) { return __uint_as_float(u << 16); }        // low bf16
__device__ __forceinline__ float bh(uint u) { return __uint_as_float(u & 0xFFFF0000u); } // high bf16

// in-block dtype detectors (wave 0 computes, LDS-broadcast by caller)
__device__ __forceinline__ int detect_isbf_w0(const void* emb) {
    int t = threadIdx.x;          // caller guarantees t < 64
    const bf16* pb = (const bf16*)emb;
    int bad = 0;
    for (int i = t; i < 256; i += 64) {
        float v = __bfloat162float(pb[i]);
        if (!(v > -1.0e6f && v < 1.0e6f)) bad++;   // f32-viewed-as-bf16 => ~42% huge/nan
    }
#pragma unroll
    for (int m = 32; m >= 1; m >>= 1) bad += __shfl_xor(bad, m, 64);
    return (bad <= 8) ? 1 : 0;
}
__device__ __forceinline__ int detect_is64_w0(const int* ei) {
    int t = threadIdx.x;          // caller guarantees t < 64
    int nz = 0;
    for (int i = 2 * t + 1; i < 256; i += 128) nz += (ei[i] != 0) ? 1 : 0;
#pragma unroll
    for (int m = 32; m >= 1; m >>= 1) nz += __shfl_xor(nz, m, 64);
    return (nz == 0) ? 1 : 0;
}

// ---------- CSR-build-in-LDS (L1 only; L2 reloads the persisted result) ----------
struct BuildS { int dcnt[KEYN]; int dexcl[KEYN]; int hbin[NBIN]; int hbase[NBIN]; int hcur[NBIN]; };

__device__ __forceinline__ void build_csr(
    int sbh, int n, const uint* __restrict__ srcp,
    BuildS* b, int* sEsrc, int* sRB, int* sRE, int* sPerm) {
    int t = threadIdx.x;
    for (int i = t; i < KEYN; i += 256) b->dcnt[i] = 0;
    if (t < NBIN) { b->hbin[t] = 0; b->hcur[t] = 0; }
    if (t < 64) sPerm[t] = -1;
    __syncthreads();
    for (int i = t; i < n; i += 256) {
        uint pk = srcp[i];
        int key = (int)((pk >> 17) & 63) * NCHUNK + (int)((pk & 0x1FFFFu) >> 14);
        atomicAdd(&b->dcnt[key], 1);
    }
    __syncthreads();
    int mybin = -1;
    if (t < 64) {
        const int kb = t * NCHUNK;
        int sum = 0;
#pragma unroll
        for (int j = 0; j < NCHUNK; j++) sum += b->dcnt[kb + j];
        int v = sum;                           // degree of dst-local t
        int x = v;
#pragma unroll
        for (int off = 1; off < 64; off <<= 1) {
            int u2 = __shfl_up(x, off, 64);
            if (t >= off) x += u2;
        }
        int myExcl = x - v;
        int run = myExcl;
#pragma unroll
        for (int j = 0; j < NCHUNK; j++) { b->dexcl[kb + j] = run; run += b->dcnt[kb + j]; }
        sRB[t] = myExcl;
        sRE[t] = myExcl + v;                   // total == n <= HCAP
        int dst = sbh * 64 + t;
        if (dst < N_NODES) {
            mybin = min(v, NBIN - 1);
            atomicAdd(&b->hbin[mybin], 1);
        }
    }
    __syncthreads();
    if (t < 64) {
        int hv = b->hbin[t];
        int sfx = hv;
#pragma unroll
        for (int off = 1; off < 64; off <<= 1) {
            int u2 = __shfl_down(sfx, off, 64);
            if (t + off < 64) sfx += u2;
        }
        b->hbase[t] = sfx - hv;
    }
    __syncthreads();
    if (t < 64 && mybin >= 0) {
        int r = atomicAdd(&b->hcur[mybin], 1);
        sPerm[b->hbase[mybin] + r] = t;
    }
    for (int i = t; i < n; i += 256) {
        uint pk = srcp[i];
        int key = (int)((pk >> 17) & 63) * NCHUNK + (int)((pk & 0x1FFFFu) >> 14);
        int p2 = atomicAdd(&b->dexcl[key], 1);
        sEsrc[p2] = (int)(pk & 0x1FFFF);
    }
    __syncthreads();
}

// ---------- node linear body (layer-1; self-casting from raw weight ptrs) ----------
__device__ __forceinline__ void node_linear_body32(
    const void* __restrict__ X,
    const void* Wq, const void* bq, const void* Wk, const void* bk,
    const void* Wv, const void* bv, const void* Ws, const void* bs,
    float* __restrict__ q, ushort* __restrict__ kvb, float* __restrict__ s,
    int bid, float* __restrict__ sW, float* __restrict__ sbias, float* __restrict__ sX,
    int* sFlag) {
    const int NPB = 32;           // nodes per block (TPN=8)
    int t = threadIdx.x;
    if (t < 64) { int f = detect_isbf_w0(X); if (t == 0) *sFlag = f; }
    __syncthreads();
    int isbf = *sFlag;

    for (int i = t; i < 1024; i += 256) {
        sW[i]        = ldf(Wq, i, isbf);
        sW[1024 + i] = ldf(Wk, i, isbf);
        sW[2048 + i] = ldf(Wv, i, isbf);
        sW[3072 + i] = ldf(Ws, i, isbf);
    }
    if (t < 32) {
        sbias[t]      = ldf(bq, t, isbf);
        sbias[32 + t] = ldf(bk, t, isbf);
        sbias[64 + t] = ldf(bv, t, isbf);
        sbias[96 + t] = ldf(bs, t, isbf);
    }
    const int base = bid * NPB * 32;
    if (isbf) {
        for (int i = t; i < NPB * 32; i += 256) {
            int g = base + i;
            float xv = (g < N_NODES * 32) ? __bfloat162float(((const bf16*)X)[g]) : 0.0f;
            sX[(i >> 5) * 36 + (i & 31)] = xv;
        }
    } else {
        for (int i = t; i < NPB * 32; i += 256) {
            int g = base + i;
            sX[(i >> 5) * 36 + (i & 31)] = (g < N_NODES * 32) ? ((const float*)X)[g] : 0.0f;
        }
    }
    __syncthreads();

    int l = t / 8;
    int c4 = (t % 8) * 4;
    int n = bid * NPB + l;
    if (n >= N_NODES) return;

    float xr[32];
#pragma unroll
    for (int j = 0; j < 8; j++) {
        float4 t4 = *(const float4*)&sX[l * 36 + 4 * j];
        xr[4 * j] = t4.x; xr[4 * j + 1] = t4.y; xr[4 * j + 2] = t4.z; xr[4 * j + 3] = t4.w;
    }
    float acc[4][4];
#pragma unroll
    for (int m = 0; m < 4; m++)
#pragma unroll
        for (int j = 0; j < 4; j++) acc[m][j] = sbias[m * 32 + c4 + j];

#pragma unroll
    for (int tt = 0; tt < 32; tt++) {
#pragma unroll
        for (int m = 0; m < 4; m++) {
            float4 w = *(const float4*)&sW[(m * 32 + tt) * 32 + c4];
            acc[m][0] += xr[tt] * w.x;
            acc[m][1] += xr[tt] * w.y;
            acc[m][2] += xr[tt] * w.z;
            acc[m][3] += xr[tt] * w.w;
        }
    }
    size_t o = (size_t)n * 32 + c4;
    *(float4*)&q[o] = make_float4(acc[0][0], acc[0][1], acc[0][2], acc[0][3]);
    *(float4*)&s[o] = make_float4(acc[3][0], acc[3][1], acc[3][2], acc[3][3]);
    size_t okv = (size_t)n * 64 + c4;
    ushort4 kp = make_ushort4(bfb(acc[1][0]), bfb(acc[1][1]), bfb(acc[1][2]), bfb(acc[1][3]));
    ushort4 vp = make_ushort4(bfb(acc[2][0]), bfb(acc[2][1]), bfb(acc[2][2]), bfb(acc[2][3]));
    *(ushort4*)&kvb[okv]      = kp;
    *(ushort4*)&kvb[okv + 32] = vp;
}

// ---------- fused: setup(block 0) || radix_a (direct scatter) || node_linear<32> ----------
struct RadixS { int cnt[NSB2P]; int gbase[NSB2P]; };
struct LinS { float sW[4096]; float sbias[128]; float sX[32 * 36]; };
union alignas(16) FusedS { RadixS r; LinS l; };

__global__ void __launch_bounds__(256, 4) fused_all(
    const int* __restrict__ ei, const void* __restrict__ emb,
    const void* Wq1, const void* bq1, const void* Wk1, const void* bk1,
    const void* Wv1, const void* bv1, const void* Ws1, const void* bs1,
    const void* Wq2, const void* bq2, const void* Wk2, const void* bk2,
    const void* Wv2, const void* bv2, const void* Ws2, const void* bs2,
    const void* Wo, const void* bo,
    int* __restrict__ flags, float* __restrict__ wp2, float* __restrict__ bp2,
    float* __restrict__ woF,
    int* __restrict__ curSB, uint* __restrict__ pairsSB,
    float* __restrict__ q, ushort* __restrict__ kvb, float* __restrict__ s) {
    __shared__ FusedS u;
    __shared__ int sFlag;
    int t = threadIdx.x;

    if (blockIdx.x == 0) {
        // ---- residual setup: flags + gather-stage params (wp2/bp2/woF) ----
        if (t < 64) {
            int f0 = detect_isbf_w0(emb);
            int f1 = detect_is64_w0(ei);
            if (t == 0) { flags[0] = f0; flags[1] = f1; sFlag = f0; }
        }
        __syncthreads();
        int isbf = sFlag;
        for (int i = t; i < 512; i += 256) {
            wp2[i]        = ldf(Wq2, i, isbf);
            wp2[512 + i]  = ldf(Wk2, i, isbf);
            wp2[1024 + i] = ldf(Wv2, i, isbf);
            wp2[1536 + i] = ldf(Ws2, i, isbf);
        }
        if (t < 32) woF[t] = ldf(Wo, t, isbf);
        if (t < 16) {
            bp2[t] = ldf(bq2, t, isbf); bp2[16 + t] = ldf(bk2, t, isbf);
            bp2[32 + t] = ldf(bv2, t, isbf); bp2[48 + t] = ldf(bs2, t, isbf);
        }
        if (t < 2) woF[32 + t] = ldf(bo, t, isbf);
        return;
    }
    if (blockIdx.x > G_RAD) {
        node_linear_body32(emb, Wq1, bq1, Wk1, bk1, Wv1, bv1, Ws1, bs1,
                           q, kvb, s, (int)blockIdx.x - 1 - G_RAD,
                           u.l.sW, u.l.sbias, u.l.sX, &sFlag);
        return;
    }
    // ---- radix_a body: count + direct scatter into 1568 dst-buckets (dst>>6) ----
    int* cnt = u.r.cnt; int* gbase = u.r.gbase;
    int rblk = (int)blockIdx.x - 1;
    for (int i = t; i < NSB2P; i += 256) cnt[i] = 0;
    if (t < 64) { int f = detect_is64_w0(ei); if (t == 0) sFlag = f; }
    __syncthreads();
    const int is64 = sFlag;
    long base = (long)rblk * RND;

    int mySb[EPB]; int myRank[EPB]; uint myPk[EPB];
#pragma unroll
    for (int r = 0; r < EPB; r++) {
        long e = base + r * 256 + t;
        mySb[r] = -1;
        if (e < N_EDGES_C) {
            int d = ldidx(ei, (long)N_EDGES_C + e, is64);
            int src = ldidx(ei, e, is64);
            int sb = d >> 6;                       // 0..1562
            myPk[r] = (uint)src | ((uint)(d & 63) << 17);
            myRank[r] = atomicAdd(&cnt[sb], 1);
            mySb[r] = sb;
        }
    }
    __syncthreads();
    for (int i = t; i < NSB2P; i += 256)
        gbase[i] = (cnt[i] > 0) ? atomicAdd(&curSB[i], cnt[i]) : 0;
    __syncthreads();
#pragma unroll
    for (int r = 0; r < EPB; r++) {
        if (mySb[r] >= 0) {
            int gp = gbase[mySb[r]] + myRank[r];
            if (gp < HCAP)
                pairsSB[(size_t)mySb[r] * HCAP + gp] = myPk[r];
        }
    }
}

// ---------- gather L1: build CSR in LDS, PERSIST it to global, gather + fused L2 linear ----------
__global__ void gather_attn_l1(const int* __restrict__ curSB, const uint* __restrict__ pairsSB,
                               const float* __restrict__ q, const ushort* __restrict__ kvb,
                               const float* __restrict__ s,
                               const float* __restrict__ wp2,   // [4][32][16] f32
                               const float* __restrict__ bp2,   // [4][16] f32
                               float* __restrict__ q2o, ushort* __restrict__ kvb2o,
                               float* __restrict__ s2o,
                               int* __restrict__ esrcG, int* __restrict__ metaG) {
    const int D = 32;
    const int LPD = 4;       // lanes per dst
    const int G = 16;        // dst groups per wave
    __shared__ float sW2[2048];
    __shared__ float sb2[64];
    union GU { BuildS b; float sH[64 * 36]; };   // build arrays dead before sH is written
    __shared__ GU gu;
    __shared__ int sEsrc[HCAP];                  // 6 KB
    __shared__ int sDst[64], sPerm[64], sRB[64], sRE[64];

    int sbh = blockIdx.x;
    int n = min(curSB[sbh], HCAP);
    for (int i = threadIdx.x; i < 2048; i += 256) sW2[i] = wp2[i];
    if (threadIdx.x < 64) sb2[threadIdx.x] = bp2[threadIdx.x];
    build_csr(sbh, n, pairsSB + (size_t)sbh * HCAP, &gu.b, sEsrc, sRB, sRE, sPerm);

    // persist the built CSR for gather_l2 (coalesced; overlaps the gather below)
    {
        int* eg = esrcG + (size_t)sbh * HCAP;
        for (int i = threadIdx.x; i < n; i += 256) eg[i] = sEsrc[i];
        if (threadIdx.x < 64) {
            int* mg = metaG + (size_t)sbh * 192;
            mg[threadIdx.x]       = sRB[threadIdx.x];
            mg[64 + threadIdx.x]  = sRE[threadIdx.x];
            mg[128 + threadIdx.x] = sPerm[threadIdx.x];
        }
    }

    int lane = threadIdx.x & 63;
    int wave = threadIdx.x >> 6;       // block-local wave 0..3
    int g = lane / LPD;
    int c = lane % LPD;                // dims 8c..8c+7
    int rank = wave * G + g;           // 0..63, degree-descending
    int dl = sPerm[rank];              // dst-local; -1 = pad
    bool alive = (dl >= 0);            // predicate (no early return -> barrier-safe)
    int dst = sbh * 64 + dl;

    const float rsq = 0.17677669529663689f;  // 1/sqrt(32)
    float4 qa = make_float4(0.f, 0.f, 0.f, 0.f), qb = qa;
    int beg = 0, end = 0;
    if (alive) {
        qa = *(const float4*)(q + (size_t)dst * D + 8 * c);
        qb = *(const float4*)(q + (size_t)dst * D + 8 * c + 4);
        beg = sRB[dl]; end = sRE[dl];
    }

    const char* kvbase = (const char*)kvb;
    const int ROW = 4 * D;            // 128 B: [k bf16 x 32 | v bf16 x 32]
    const int koff = 16 * c;
    const int voff = 2 * D + 16 * c;

    float sum0 = 0.f, sum1 = 0.f;
    float a0[8] = {0,0,0,0,0,0,0,0};
    float a1[8] = {0,0,0,0,0,0,0,0};

    uint4 kq[4], vq[4];
#pragma unroll
    for (int r = 0; r < 4; r++) {
        int sn = (beg + r < end) ? sEsrc[beg + r] : 0;
        const char* p = kvbase + (size_t)sn * ROW;
        kq[r] = *(const uint4*)(p + koff);
        vq[r] = *(const uint4*)(p + voff);
    }

    for (int e = beg; e < end; e += 4) {
        uint4 kc[4], vc[4];
#pragma unroll
        for (int r = 0; r < 4; r++) { kc[r] = kq[r]; vc[r] = vq[r]; }
#pragma unroll
        for (int r = 0; r < 4; r++) {
            if (e + 4 + r < end) {
                const char* p = kvbase + (size_t)sEsrc[e + 4 + r] * ROW;
                kq[r] = *(const uint4*)(p + koff);
                vq[r] = *(const uint4*)(p + voff);
            }
        }
#pragma unroll
        for (int r = 0; r < 4; r++) {
            if (e + r < end) {
                uint4 kA = kc[r], vA = vc[r];
                float pd = qa.x * bl(kA.x) + qa.y * bh(kA.x) + qa.z * bl(kA.y) + qa.w * bh(kA.y)
                         + qb.x * bl(kA.z) + qb.y * bh(kA.z) + qb.z * bl(kA.w) + qb.w * bh(kA.w);
#pragma unroll
                for (int m = LPD / 2; m >= 1; m >>= 1) pd += __shfl_xor(pd, m, LPD);
                float ex = __expf(fminf(fmaxf(pd * rsq, -80.0f), 80.0f));
                if (r & 1) {
                    sum1 += ex;
                    a1[0] += bl(vA.x) * ex; a1[1] += bh(vA.x) * ex;
                    a1[2] += bl(vA.y) * ex; a1[3] += bh(vA.y) * ex;
                    a1[4] += bl(vA.z) * ex; a1[5] += bh(vA.z) * ex;
                    a1[6] += bl(vA.w) * ex; a1[7] += bh(vA.w) * ex;
                } else {
                    sum0 += ex;
                    a0[0] += bl(vA.x) * ex; a0[1] += bh(vA.x) * ex;
                    a0[2] += bl(vA.y) * ex; a0[3] += bh(vA.y) * ex;
                    a0[4] += bl(vA.z) * ex; a0[5] += bh(vA.z) * ex;
                    a0[6] += bl(vA.w) * ex; a0[7] += bh(vA.w) * ex;
                }
            }
        }
    }
    float inv = 1.0f / (sum0 + sum1 + 1e-16f);
    float4 sa = make_float4(0.f, 0.f, 0.f, 0.f), sbv = sa;
    if (alive) {
        sa  = *(const float4*)(s + (size_t)dst * D + 8 * c);
        sbv = *(const float4*)(s + (size_t)dst * D + 8 * c + 4);
    }
    float h[8];
    h[0] = (a0[0] + a1[0]) * inv + sa.x;  h[1] = (a0[1] + a1[1]) * inv + sa.y;
    h[2] = (a0[2] + a1[2]) * inv + sa.z;  h[3] = (a0[3] + a1[3]) * inv + sa.w;
    h[4] = (a0[4] + a1[4]) * inv + sbv.x; h[5] = (a0[5] + a1[5]) * inv + sbv.y;
    h[6] = (a0[6] + a1[6]) * inv + sbv.z; h[7] = (a0[7] + a1[7]) * inv + sbv.w;
#pragma unroll
    for (int j = 0; j < 8; j++) h[j] = h[j] > 0.0f ? h[j] : 0.0f;

    // fused layer-2 node linear via LDS transpose (identical accumulation order
    // to the standalone node_linear<16>); 64 nodes per block.
    int gl = wave * G + g;                    // 0..63: block-local node slot
    if (alive) {
        *(float4*)&gu.sH[gl * 36 + 8 * c]     = make_float4(h[0], h[1], h[2], h[3]);
        *(float4*)&gu.sH[gl * 36 + 8 * c + 4] = make_float4(h[4], h[5], h[6], h[7]);
    }
    if (c == 0) sDst[gl] = alive ? dst : -1;
    __syncthreads();
    int l = threadIdx.x >> 2;                 // node slot 0..63
    int c4 = (threadIdx.x & 3) * 4;           // output dims c4..c4+3
    int nd = sDst[l];
    if (nd >= 0) {
        float acc2[4][4];
#pragma unroll
        for (int m = 0; m < 4; m++)
#pragma unroll
            for (int j = 0; j < 4; j++) acc2[m][j] = sb2[m * 16 + c4 + j];
#pragma unroll
        for (int t2 = 0; t2 < 32; t2++) {
            float xv = gu.sH[l * 36 + t2];
#pragma unroll
            for (int m = 0; m < 4; m++) {
                float4 w = *(const float4*)&sW2[(m * 32 + t2) * 16 + c4];
                acc2[m][0] += xv * w.x;
                acc2[m][1] += xv * w.y;
                acc2[m][2] += xv * w.z;
                acc2[m][3] += xv * w.w;
            }
        }
        size_t o = (size_t)nd * 16 + c4;
        *(float4*)&q2o[o] = make_float4(acc2[0][0], acc2[0][1], acc2[0][2], acc2[0][3]);
        *(float4*)&s2o[o] = make_float4(acc2[3][0], acc2[3][1], acc2[3][2], acc2[3][3]);
        size_t okv = (size_t)nd * 32 + c4;
        ushort4 kp = make_ushort4(bfb(acc2[1][0]), bfb(acc2[1][1]), bfb(acc2[1][2]), bfb(acc2[1][3]));
        ushort4 vp = make_ushort4(bfb(acc2[2][0]), bfb(acc2[2][1]), bfb(acc2[2][2]), bfb(acc2[2][3]));
        *(ushort4*)&kvb2o[okv]      = kp;
        *(ushort4*)&kvb2o[okv + 16] = vp;
    }
}

// ---------- gather L2: reload persisted CSR (coalesced) + whole-row gather ----------
__global__ void gather_attn_l2(const int* __restrict__ curSB,
                               const int* __restrict__ esrcG, const int* __restrict__ metaG,
                               const float* __restrict__ q, const ushort* __restrict__ kvb,
                               const float* __restrict__ s,
                               const float* __restrict__ woF,   // [32]=Wo, [32..33]=bo
                               const int* __restrict__ flags,
                               void* __restrict__ out) {
    const int D = 16;
    const int LG = 4;             // lanes per dst group = row bytes / 16
    const int KL = 2;             // k-lanes per group
    const int G  = 16;            // dsts per wave
    __shared__ int sEsrc[HCAP];
    __shared__ int sPerm[64], sRB[64], sRE[64];

    int sbh = blockIdx.x;
    int n = min(curSB[sbh], HCAP);
    {   // coalesced reload of the CSR gather_l1 built (identical content/order)
        const int* eg = esrcG + (size_t)sbh * HCAP;
        for (int i = threadIdx.x; i < n; i += 256) sEsrc[i] = eg[i];
        if (threadIdx.x < 64) {
            const int* mg = metaG + (size_t)sbh * 192;
            sRB[threadIdx.x]   = mg[threadIdx.x];
            sRE[threadIdx.x]   = mg[64 + threadIdx.x];
            sPerm[threadIdx.x] = mg[128 + threadIdx.x];
        }
    }
    __syncthreads();
    // no barriers below -> early returns are safe

    int lane = threadIdx.x & 63;
    int wave = threadIdx.x >> 6;
    int g = lane / LG;
    int sub = lane % LG;          // 16B chunk of the row this lane owns
    bool isK = (sub < KL);
    int cv = sub - KL;            // v-lane dim chunk (dims 8cv..8cv+7)
    int rank = wave * G + g;
    int dl = sPerm[rank];
    if (dl < 0) return;
    int dst = sbh * 64 + dl;

    const float rsq = 0.25f;      // 1/sqrt(16)
    float qacc[8] = {0,0,0,0,0,0,0,0};
    if (isK) {
        float4 qa = *(const float4*)(q + (size_t)dst * D + 8 * sub);
        float4 qb = *(const float4*)(q + (size_t)dst * D + 8 * sub + 4);
        qacc[0] = qa.x; qacc[1] = qa.y; qacc[2] = qa.z; qacc[3] = qa.w;
        qacc[4] = qb.x; qacc[5] = qb.y; qacc[6] = qb.z; qacc[7] = qb.w;
    }
    int beg = sRB[dl], end = sRE[dl];

    const char* kvbase = (const char*)kvb + 16 * sub;   // this lane's chunk offset
    const int ROW = 4 * D;        // 64 B: [k bf16 x 16 | v bf16 x 16], row-aligned

    float sum = 0.f;

    uint4 rv[4];
    int sn1[4];
#pragma unroll
    for (int r = 0; r < 4; r++) {
        int sn = (beg + r < end) ? sEsrc[beg + r] : 0;
        rv[r] = *(const uint4*)(kvbase + (size_t)sn * ROW);
    }
#pragma unroll
    for (int r = 0; r < 4; r++)
        sn1[r] = (beg + 4 + r < end) ? sEsrc[beg + 4 + r] : 0;

    for (int e = beg; e < end; e += 4) {
        uint4 rc[4];
#pragma unroll
        for (int r = 0; r < 4; r++) rc[r] = rv[r];
#pragma unroll
        for (int r = 0; r < 4; r++) {
            if (e + 4 + r < end)
                rv[r] = *(const uint4*)(kvbase + (size_t)sn1[r] * ROW);
        }
#pragma unroll
        for (int r = 0; r < 4; r++) {
            if (e + 8 + r < end) sn1[r] = sEsrc[e + 8 + r];
        }
#pragma unroll
        for (int r = 0; r < 4; r++) {
            if (e + r < end) {
                uint4 rA = rc[r];
                float pd = 0.f;
                if (isK) {
                    pd = qacc[0] * bl(rA.x) + qacc[1] * bh(rA.x)
                       + qacc[2] * bl(rA.y) + qacc[3] * bh(rA.y)
                       + qacc[4] * bl(rA.z) + qacc[5] * bh(rA.z)
                       + qacc[6] * bl(rA.w) + qacc[7] * bh(rA.w);
                }
                pd += __shfl_xor(pd, 1, KL);            // reduce across 2 k-lanes
                float pdx = __shfl_xor(pd, KL, LG);     // k->v broadcast
                float pdf = isK ? pd : pdx;
                float ex = __expf(fminf(fmaxf(pdf * rsq, -80.0f), 80.0f));
                sum += ex;
                if (!isK) {
                    qacc[0] += bl(rA.x) * ex; qacc[1] += bh(rA.x) * ex;
                    qacc[2] += bl(rA.y) * ex; qacc[3] += bh(rA.y) * ex;
                    qacc[4] += bl(rA.z) * ex; qacc[5] += bh(rA.z) * ex;
                    qacc[6] += bl(rA.w) * ex; qacc[7] += bh(rA.w) * ex;
                }
            }
        }
    }
    float inv = 1.0f / (sum + 1e-16f);   // sum identical on all LG lanes of the group
    float p0 = 0.f, p1 = 0.f;
    if (!isK) {
        float4 sa  = *(const float4*)(s + (size_t)dst * D + 8 * cv);
        float4 sbv = *(const float4*)(s + (size_t)dst * D + 8 * cv + 4);
        float h[8];
        h[0] = qacc[0] * inv + sa.x;  h[1] = qacc[1] * inv + sa.y;
        h[2] = qacc[2] * inv + sa.z;  h[3] = qacc[3] * inv + sa.w;
        h[4] = qacc[4] * inv + sbv.x; h[5] = qacc[5] * inv + sbv.y;
        h[6] = qacc[6] * inv + sbv.z; h[7] = qacc[7] * inv + sbv.w;
#pragma unroll
        for (int j = 0; j < 8; j++) h[j] = h[j] > 0.0f ? h[j] : 0.0f;
#pragma unroll
        for (int j = 0; j < 8; j++) {
            p0 += h[j] * woF[(8 * cv + j) * 2 + 0];
            p1 += h[j] * woF[(8 * cv + j) * 2 + 1];
        }
    }
    p0 += __shfl_xor(p0, 1, 2);
    p1 += __shfl_xor(p1, 1, 2);
    if (sub == KL) {
        float o0 = p0 + woF[32];
        float o1 = p1 + woF[33];
        if (flags[0]) {
            ((bf16*)out)[dst * 2 + 0] = __float2bfloat16(o0);
            ((bf16*)out)[dst * 2 + 1] = __float2bfloat16(o1);
        } else {
            ((float*)out)[dst * 2 + 0] = o0;
            ((float*)out)[dst * 2 + 1] = o1;
        }
    }
}

extern "C" void kernel_launch(void* const* d_in, const int* in_sizes, int n_in,
                              void* d_out, int out_size, void* d_ws, size_t ws_size,
                              hipStream_t stream) {
    const int* ei  = (const int*)d_in[0];
    const void* emb = d_in[1];
    const void *Wq1 = d_in[2],  *bq1 = d_in[3];
    const void *Wk1 = d_in[4],  *bk1 = d_in[5];
    const void *Wv1 = d_in[6],  *bv1 = d_in[7];
    const void *Ws1 = d_in[8],  *bs1 = d_in[9];
    const void *Wq2 = d_in[10], *bq2 = d_in[11];
    const void *Wk2 = d_in[12], *bk2 = d_in[13];
    const void *Wv2 = d_in[14], *bv2 = d_in[15];
    const void *Ws2 = d_in[16], *bs2 = d_in[17];
    const void *Wo  = d_in[18], *bo  = d_in[19];

    const size_t ND   = (size_t)N_NODES * 32;   // 3.2M floats
    const size_t ND16 = (size_t)N_NODES * 16;   // 1.6M floats
    const size_t SBTOT = (size_t)NSB2 * HCAP;   // 2,408,448 (pairsSB, esrcG)
    float* base   = (float*)d_ws;
    int*   flags  = (int*)base;                  // 64
    float* wp2    = base + 64;                   // 2048
    float* bp2    = wp2 + 2048;                  // 64
    float* woF    = bp2 + 64;                    // 64
    int*   curSB  = (int*)(woF + 64);            // NSB2P (1792)
    float* p      = (float*)(curSB + NSB2P);
    p = (float*)(((uintptr_t)p + 127) & ~(uintptr_t)127);   // 128B-align kv rows
    float* q      = p; p += ND;                  // layer-1 q (f32)
    float* s      = p; p += ND;                  // layer-1 skip (f32)
    ushort* kvb   = (ushort*)p; p += ND;         // layer-1 k|v packed bf16 (128B rows)
    float* q2     = p; p += ND16;                // layer-2 q
    float* s2     = p; p += ND16;                // layer-2 skip
    ushort* kvb2  = (ushort*)p; p += ND16;       // layer-2 k|v packed bf16 (64B rows)
    uint*  pairsSB = (uint*)p; p += SBTOT;       // 9.6 MB
    int*   esrcG  = (int*)p; p += SBTOT;         // 9.6 MB (persisted CSR payload)
    int*   metaG  = (int*)p;                     // NSB2*192 ints (1.2 MB: RB|RE|Perm)
    // total ~ 81 MB

    const int B = 256;
    const int gNL32  = (N_NODES + 31) / 32;      // 3125
    const int gFused = 1 + G_RAD + gNL32;        // setup block + radix + NL

    // 0: zero bucket counters (stream-ordered, graph-capturable)
    hipMemsetAsync(curSB, 0, NSB2P * sizeof(int), stream);

    // 1: setup(block 0) || radix pass A (direct scatter) || layer-1 node linears
    fused_all<<<gFused, B, 0, stream>>>(ei, emb,
        Wq1, bq1, Wk1, bk1, Wv1, bv1, Ws1, bs1,
        Wq2, bq2, Wk2, bk2, Wv2, bv2, Ws2, bs2, Wo, bo,
        flags, wp2, bp2, woF, curSB, pairsSB, q, kvb, s);

    // 2: layer-1 attention (CSR built in-block, persisted for L2) + relu + fused L2 linear
    gather_attn_l1<<<NSB2, B, 0, stream>>>(
        curSB, pairsSB, q, kvb, s, wp2, bp2, q2, kvb2, s2, esrcG, metaG);

    // 3: layer-2 attention (CSR reloaded coalesced) + relu + output linear
    gather_attn_l2<<<NSB2, B, 0, stream>>>(
        curSB, esrcG, metaG, q2, kvb2, s2, woF, flags, d_out);
}